// Round 9
// baseline (188.522 us; speedup 1.0000x reference)
//
#include <hip/hip_runtime.h>
#include <float.h>
#include <math.h>

#define B_SZ   2048
#define D_DIM  256
#define P_DIM  4
#define N_TOT  4096        // 2*B
#define EPS_F  1e-8f
#define NB     1024        // buckets over ld in [0,4): width 1/256
#define BSCALE 256.0f

typedef short  s16x8 __attribute__((ext_vector_type(8)));
typedef float  f32x4 __attribute__((ext_vector_type(4)));

__device__ __forceinline__ void async_load16(const void* g, const void* l) {
    __builtin_amdgcn_global_load_lds(
        (const __attribute__((address_space(1))) unsigned int*)g,
        (__attribute__((address_space(3))) unsigned int*)l,
        16, 0, 0);
}

__device__ __forceinline__ unsigned short f2bf(float x) {
    unsigned int b = __float_as_uint(x);
    b += 0x7FFFu + ((b >> 16) & 1u);        // RNE
    return (unsigned short)(b >> 16);
}

__device__ __forceinline__ float bf_extract(unsigned u, int hi) {
    return __uint_as_float(hi ? (u & 0xFFFF0000u) : (u << 16));
}

// ---------------- Kernel A: row-normalize features -> bf16 ----------------
__global__ __launch_bounds__(64) void normalize_kernel(
    const float* __restrict__ z_i, const float* __restrict__ z_j,
    unsigned short* __restrict__ fb)
{
    int row  = blockIdx.x;
    int lane = threadIdx.x;
    const float* src = (row < B_SZ) ? (z_i + (size_t)row * D_DIM)
                                    : (z_j + (size_t)(row - B_SZ) * D_DIM);
    float4 v = ((const float4*)src)[lane];
    float ss = v.x*v.x + v.y*v.y + v.z*v.z + v.w*v.w;
    #pragma unroll
    for (int off = 32; off > 0; off >>= 1)
        ss += __shfl_down(ss, off, 64);
    ss = __shfl(ss, 0, 64);
    float inv = 1.0f / sqrtf(ss);
    ushort4 o;
    o.x = f2bf(v.x * inv); o.y = f2bf(v.y * inv);
    o.z = f2bf(v.z * inv); o.w = f2bf(v.w * inv);
    ((ushort4*)(fb + (size_t)row * D_DIM))[lane] = o;
}

// ------- Kernel B: logits = f @ f^T / TEMP, bf16 MFMA, 128x128, LDS dbuf -------
// One barrier per K-iter; prefetch of tile k+1 issued before compute of tile k.
__global__ __launch_bounds__(256, 4) void gemm_kernel(
    const unsigned short* __restrict__ fb, unsigned short* __restrict__ out)
{
    __shared__ unsigned short As[2][128 * 32];   // 16 KB
    __shared__ unsigned short Bs[2][128 * 32];   // 16 KB

    int tid = threadIdx.x;
    int w   = tid >> 6;
    int L   = tid & 63;
    int bm  = blockIdx.y * 128;
    int bn  = blockIdx.x * 128;

    f32x4 acc[4][4];
    #pragma unroll
    for (int r = 0; r < 4; ++r)
        #pragma unroll
        for (int c = 0; c < 4; ++c)
            #pragma unroll
            for (int q = 0; q < 4; ++q) acc[r][c][q] = 0.f;

    const int wr = (w >> 1) * 64;
    const int wc = (w & 1) * 64;
    const int rowbase = (w < 2) ? (bm + w * 64) : (bn + (w - 2) * 64);
    const int lrow    = (L >> 2) * 32;            // row-within-chunk * 32 elems
    const int lcol    = (L & 3) * 8;

    // stage(buf, k0): wave w stages its 64-row half-chunk (4 x 16 rows)
    #define STAGE(buf, k0)                                                     \
        {                                                                      \
            unsigned short* lchunk = (w < 2) ? (As[buf] + w * 2048)            \
                                             : (Bs[buf] + (w - 2) * 2048);     \
            _Pragma("unroll")                                                  \
            for (int c = 0; c < 4; ++c) {                                      \
                int grow = rowbase + c * 16 + (L >> 2);                        \
                const unsigned short* g =                                      \
                    fb + (size_t)grow * D_DIM + (k0) + lcol;                   \
                async_load16(g, lchunk + c * 512);                             \
            }                                                                  \
        }

    STAGE(0, 0);

    #pragma unroll
    for (int it = 0; it < 8; ++it) {
        __syncthreads();                       // staging of buf it&1 complete
        if (it < 7) STAGE((it + 1) & 1, (it + 1) * 32);   // prefetch next

        int buf  = it & 1;
        int koff = (L >> 4) * 8;
        s16x8 a[4], b[4];
        #pragma unroll
        for (int rt = 0; rt < 4; ++rt)
            a[rt] = *(const s16x8*)(As[buf] + (wr + rt * 16 + (L & 15)) * 32 + koff);
        #pragma unroll
        for (int ct = 0; ct < 4; ++ct)
            b[ct] = *(const s16x8*)(Bs[buf] + (wc + ct * 16 + (L & 15)) * 32 + koff);
        #pragma unroll
        for (int rt = 0; rt < 4; ++rt)
            #pragma unroll
            for (int ct = 0; ct < 4; ++ct)
                acc[rt][ct] = __builtin_amdgcn_mfma_f32_16x16x32_bf16(
                    a[rt], b[ct], acc[rt][ct], 0, 0, 0);
    }
    #undef STAGE

    #pragma unroll
    for (int rt = 0; rt < 4; ++rt) {
        #pragma unroll
        for (int ct = 0; ct < 4; ++ct) {
            int col = bn + wc + ct * 16 + (L & 15);
            #pragma unroll
            for (int q = 0; q < 4; ++q) {
                int row = bm + wr + rt * 16 + (L >> 4) * 4 + q;
                out[(size_t)row * N_TOT + col] = f2bf(acc[rt][ct][q] * 0.5f); // /TEMP
            }
        }
    }
}

// -------- Kernel C: 2 rows/block, dual histogram (e-sum + count), NB=1024 --------
// denom for bucket b = inclusive suffix S[b]; per-row logsum = sum_b cnt[b]*log(S[b]).
// Tie-approx error well under threshold (empirically ~0 at finer NB).
__global__ __launch_bounds__(256, 8) void row_kernel(
    const unsigned short* __restrict__ logits,
    const float* __restrict__ physics_i, const float* __restrict__ physics_j,
    float* __restrict__ rowres)
{
    __shared__ float    bs0[NB];             // 4 KB  e-sum histogram row0
    __shared__ float    bs1[NB];             // 4 KB  row1
    __shared__ unsigned cw0[NB / 2];         // 2 KB  packed u16 counts row0
    __shared__ unsigned cw1[NB / 2];         // 2 KB  row1
    __shared__ float    scr[48];

    int tid  = threadIdx.x;
    int lane = tid & 63;
    int wid  = tid >> 6;
    int i0   = blockIdx.x * 2;
    int i1   = i0 + 1;

    // coalesced bf16 logit loads for both rows (2 x dwordx4 each)
    const unsigned short* lp0 = logits + (size_t)i0 * N_TOT + tid * 16;
    const unsigned short* lp1 = logits + (size_t)i1 * N_TOT + tid * 16;
    uint4 r0a = *(const uint4*)lp0;
    uint4 r0b = *(const uint4*)(lp0 + 8);
    uint4 r1a = *(const uint4*)lp1;
    uint4 r1b = *(const uint4*)(lp1 + 8);

    #pragma unroll
    for (int t = 0; t < 4; ++t) { bs0[tid + t * 256] = 0.f; bs1[tid + t * 256] = 0.f; }
    #pragma unroll
    for (int t = 0; t < 2; ++t) { cw0[tid + t * 256] = 0u;  cw1[tid + t * 256] = 0u; }

    const float* Lp0 = (i0 < B_SZ) ? (physics_i + (size_t)i0 * P_DIM)
                                   : (physics_j + (size_t)(i0 - B_SZ) * P_DIM);
    const float* Lp1 = (i1 < B_SZ) ? (physics_i + (size_t)i1 * P_DIM)
                                   : (physics_j + (size_t)(i1 - B_SZ) * P_DIM);
    float4 Li0 = *(const float4*)Lp0;
    float4 Li1 = *(const float4*)Lp1;
    __syncthreads();                                   // B0: zeros visible

    unsigned raws0[8] = { r0a.x, r0a.y, r0a.z, r0a.w, r0b.x, r0b.y, r0b.z, r0b.w };
    unsigned raws1[8] = { r1a.x, r1a.y, r1a.z, r1a.w, r1b.x, r1b.y, r1b.z, r1b.w };

    // phase 1: shared physics gather (4-deep batches), dual histograms
    float sl0 = 0.f, sl1 = 0.f;
    #pragma unroll
    for (int h = 0; h < 4; ++h) {
        float4 Lj[4];
        #pragma unroll
        for (int t = 0; t < 4; ++t) {
            int j = tid * 16 + h * 4 + t;
            const float* p = (j < B_SZ) ? (physics_i + (size_t)j * P_DIM)
                                        : (physics_j + (size_t)(j - B_SZ) * P_DIM);
            Lj[t] = *(const float4*)p;
        }
        #pragma unroll
        for (int t = 0; t < 4; ++t) {
            int tt = h * 4 + t;
            int j  = tid * 16 + tt;
            float l0 = bf_extract(raws0[tt >> 1], tt & 1);
            float l1 = bf_extract(raws1[tt >> 1], tt & 1);
            float d0 = fabsf(Li0.x - Lj[t].x) + fabsf(Li0.y - Lj[t].y)
                     + fabsf(Li0.z - Lj[t].z) + fabsf(Li0.w - Lj[t].w);
            float d1 = fabsf(Li1.x - Lj[t].x) + fabsf(Li1.y - Lj[t].y)
                     + fabsf(Li1.z - Lj[t].z) + fabsf(Li1.w - Lj[t].w);
            int b0 = (int)(d0 * BSCALE); if (b0 > NB - 1) b0 = NB - 1;
            int b1 = (int)(d1 * BSCALE); if (b1 > NB - 1) b1 = NB - 1;
            if (j != i0) {
                sl0 += l0;
                atomicAdd(&bs0[b0], __expf(l0));
                atomicAdd(&cw0[b0 >> 1], 1u << ((b0 & 1) * 16));
            }
            if (j != i1) {
                sl1 += l1;
                atomicAdd(&bs1[b1], __expf(l1));
                atomicAdd(&cw1[b1 >> 1], 1u << ((b1 & 1) * 16));
            }
        }
    }
    #pragma unroll
    for (int off = 32; off > 0; off >>= 1) {
        sl0 += __shfl_down(sl0, off, 64);
        sl1 += __shfl_down(sl1, off, 64);
    }
    if (lane == 0) { scr[wid] = sl0; scr[4 + wid] = sl1; }
    __syncthreads();                                   // B1: hists + sl ready
    float slo0 = scr[0] + scr[1] + scr[2] + scr[3];
    float slo1 = scr[4] + scr[5] + scr[6] + scr[7];

    // phase 2: suffix scan in registers; ownership b = k*256+tid (conflict-free)
    float s0[4], s1[4];
    #pragma unroll
    for (int k = 0; k < 4; ++k) { s0[k] = bs0[k * 256 + tid]; s1[k] = bs1[k * 256 + tid]; }
    #pragma unroll
    for (int off = 1; off < 64; off <<= 1) {
        #pragma unroll
        for (int k = 0; k < 4; ++k) {
            float u0 = __shfl_down(s0[k], off, 64);
            float u1 = __shfl_down(s1[k], off, 64);
            if (lane + off < 64) { s0[k] += u0; s1[k] += u1; }
        }
    }
    if (lane == 0) {
        #pragma unroll
        for (int k = 0; k < 4; ++k) { scr[8 + k * 4 + wid] = s0[k]; scr[24 + k * 4 + wid] = s1[k]; }
    }
    __syncthreads();                                   // B2: wave totals ready

    // combine: S_own[k] = s[k] + (later waves in slice k) + (full totals of slices > k)
    float T0[4], T1[4], cr0[4], cr1[4];
    #pragma unroll
    for (int k = 0; k < 4; ++k) {
        T0[k] = 0.f; T1[k] = 0.f; cr0[k] = 0.f; cr1[k] = 0.f;
        #pragma unroll
        for (int ww = 0; ww < 4; ++ww) {
            float a = scr[8 + k * 4 + ww], b = scr[24 + k * 4 + ww];
            T0[k] += a; T1[k] += b;
            if (ww > wid) { cr0[k] += a; cr1[k] += b; }
        }
    }
    float hi0 = 0.f, hi1 = 0.f;
    float logsum0 = 0.f, logsum1 = 0.f;
    #pragma unroll
    for (int k = 3; k >= 0; --k) {
        float S0 = s0[k] + cr0[k] + hi0;               // inclusive suffix at bucket k*256+tid
        float S1 = s1[k] + cr1[k] + hi1;
        hi0 += T0[k]; hi1 += T1[k];
        unsigned w0 = cw0[k * 128 + (tid >> 1)];       // 2-lane broadcast
        unsigned w1 = cw1[k * 128 + (tid >> 1)];
        float c0 = (float)((w0 >> ((tid & 1) * 16)) & 0xFFFFu);
        float c1 = (float)((w1 >> ((tid & 1) * 16)) & 0xFFFFu);
        logsum0 = fmaf(c0, __logf(S0 + EPS_F), logsum0);
        logsum1 = fmaf(c1, __logf(S1 + EPS_F), logsum1);
    }
    #pragma unroll
    for (int off = 32; off > 0; off >>= 1) {
        logsum0 += __shfl_down(logsum0, off, 64);
        logsum1 += __shfl_down(logsum1, off, 64);
    }
    if (lane == 0) { scr[40 + wid] = logsum0; scr[44 + wid] = logsum1; }
    __syncthreads();                                   // B3
    if (tid == 0) {
        rowres[i0] = (scr[40] + scr[41] + scr[42] + scr[43]) - slo0;
        rowres[i1] = (scr[44] + scr[45] + scr[46] + scr[47]) - slo1;
    }
}

// ---------------- Kernel D: final reduce ----------------
__global__ __launch_bounds__(256) void final_kernel(
    const float* __restrict__ rowres, float* __restrict__ out)
{
    __shared__ float red[4];
    int tid = threadIdx.x;
    float s = 0.f;
    for (int i = tid; i < N_TOT; i += 256) s += rowres[i];
    #pragma unroll
    for (int off = 32; off > 0; off >>= 1)
        s += __shfl_down(s, off, 64);
    if ((tid & 63) == 0) red[tid >> 6] = s;
    __syncthreads();
    if (tid == 0) {
        double tot = (double)red[0] + red[1] + red[2] + red[3];
        out[0] = (float)(tot / ((double)N_TOT * (N_TOT - 1)));
    }
}

extern "C" void kernel_launch(void* const* d_in, const int* in_sizes, int n_in,
                              void* d_out, int out_size, void* d_ws, size_t ws_size,
                              hipStream_t stream)
{
    const float* z_i  = (const float*)d_in[0];
    const float* z_j  = (const float*)d_in[1];
    const float* ph_i = (const float*)d_in[2];
    const float* ph_j = (const float*)d_in[3];

    unsigned short* fb     = (unsigned short*)d_ws;                        // 2 MB bf16
    unsigned short* logits = fb + (size_t)N_TOT * D_DIM;                   // 32 MB bf16
    float*          rowres = (float*)(logits + (size_t)N_TOT * N_TOT);     // 16 KB

    normalize_kernel<<<N_TOT, 64, 0, stream>>>(z_i, z_j, fb);
    dim3 g(N_TOT / 128, N_TOT / 128);
    gemm_kernel<<<g, 256, 0, stream>>>(fb, logits);
    row_kernel<<<N_TOT / 2, 256, 0, stream>>>(logits, ph_i, ph_j, rowres);
    final_kernel<<<1, 256, 0, stream>>>(rowres, (float*)d_out);
}